// Round 8
// baseline (119.395 us; speedup 1.0000x reference)
//
#include <hip/hip_runtime.h>
#include <hip/hip_bf16.h>
#include <cstdint>

// Problem constants
#define N_TOK 4096   // B*T
#define D_    1024
#define E_    8
#define I_    512
#define KTOP  2
#define PAD   64     // expert segments padded to 64 (tile M)
#define BK    64     // K-step
#define CAP   (N_TOK*KTOP + E_*PAD)   // 8704 max padded positions
#define NBX   (CAP / PAD)             // 136 position tiles (17 per XCD)
#define WSZ   ((size_t)E_ * I_ * D_)  // one weight's element count

typedef __attribute__((ext_vector_type(4))) float f32x4;
typedef __attribute__((ext_vector_type(8))) short bf16x8;

__device__ inline unsigned short f2bf(float f) {
  union { float f; uint32_t u; } v; v.f = f;
  uint32_t r = v.u + 0x7fffu + ((v.u >> 16) & 1u);
  return (unsigned short)(r >> 16);
}
__device__ inline float bf2f(unsigned short h) {
  union { uint32_t u; float f; } v; v.u = ((uint32_t)h) << 16;
  return v.f;
}
__device__ inline unsigned int pk2(float a, float b) {
  __hip_bfloat162 h2 = __float22bfloat162_rn(float2{a, b});
  return *reinterpret_cast<unsigned int*>(&h2);
}

#define GLOAD_LDS16(gp, lp)                                                        \
  __builtin_amdgcn_global_load_lds((const __attribute__((address_space(1))) void*)(gp), \
                                   (__attribute__((address_space(3))) void*)(lp), 16, 0, 0)

// ---------------- prep: Wg/Wu converts (blocks 0..8191) ∥ router (8192..9215) ----------------
__global__ __launch_bounds__(256) void prep_kernel(const float* __restrict__ x,
                                                   const float* __restrict__ rw,
                                                   const float* __restrict__ wg,
                                                   const float* __restrict__ wu,
                                                   float* __restrict__ logits,
                                                   int* __restrict__ sel,
                                                   float* __restrict__ prob,
                                                   unsigned short* __restrict__ Xb,
                                                   unsigned short* __restrict__ Wb) {
  int b = blockIdx.x;
  if (b < 2 * 4096) {
    const int y = b >> 12;
    const float* s = (y == 0) ? wg : wu;
    unsigned short* d = Wb + (size_t)y * WSZ;
    const int i = (b & 4095) * 256 + threadIdx.x;
    const float4 v = reinterpret_cast<const float4*>(s)[i];
    ushort4 o;
    o.x = f2bf(v.x); o.y = f2bf(v.y); o.z = f2bf(v.z); o.w = f2bf(v.w);
    reinterpret_cast<ushort4*>(d)[i] = o;
    return;
  }
  b -= 2 * 4096;   // router: 1024 blocks, 4 tokens each
  const int lane = threadIdx.x & 63;
  const int tok  = b * 4 + (threadIdx.x >> 6);
  const float4* xr = reinterpret_cast<const float4*>(x + (size_t)tok * D_);
  float4 xv[4];
#pragma unroll
  for (int q = 0; q < 4; ++q) xv[q] = xr[q * 64 + lane];
  float acc[E_];
#pragma unroll
  for (int e = 0; e < E_; ++e) {
    const float4* wr = reinterpret_cast<const float4*>(rw + (size_t)e * D_);
    float s = 0.f;
#pragma unroll
    for (int q = 0; q < 4; ++q) {
      float4 wv = wr[q * 64 + lane];
      s += xv[q].x * wv.x + xv[q].y * wv.y + xv[q].z * wv.z + xv[q].w * wv.w;
    }
    acc[e] = s;
  }
  ushort4* xb = reinterpret_cast<ushort4*>(Xb + (size_t)tok * D_);
#pragma unroll
  for (int q = 0; q < 4; ++q) {
    ushort4 o;
    o.x = f2bf(xv[q].x); o.y = f2bf(xv[q].y); o.z = f2bf(xv[q].z); o.w = f2bf(xv[q].w);
    xb[q * 64 + lane] = o;
  }
#pragma unroll
  for (int e = 0; e < E_; ++e)
#pragma unroll
    for (int off = 32; off; off >>= 1) acc[e] += __shfl_xor(acc[e], off);
  if (lane == 0) {
    float v0 = -1e30f, v1 = -1e30f; int i0 = 0, i1 = 0;
#pragma unroll
    for (int e = 0; e < E_; ++e) {
      float v = acc[e];
      logits[(size_t)tok * E_ + e] = v;
      if (v > v0)      { v1 = v0; i1 = i0; v0 = v; i0 = e; }
      else if (v > v1) { v1 = v;  i1 = e; }
    }
    float t  = __expf(v1 - v0);
    sel[tok * 2] = i0; sel[tok * 2 + 1] = i1;
    prob[tok * 2] = 1.f / (1.f + t);
    prob[tok * 2 + 1] = t / (1.f + t);
  }
}

// ---------------- plan: counts (ballot), padded offsets, scatter, pads, zbuf ----------------
__global__ __launch_bounds__(1024) void plan_kernel(const int* __restrict__ sel,
                                                    const float* __restrict__ prob,
                                                    int* __restrict__ offs,
                                                    int* __restrict__ ptok,
                                                    float* __restrict__ pprob,
                                                    int* __restrict__ tpos,
                                                    unsigned int* __restrict__ zbuf) {
  __shared__ int wcnt[16][E_];
  __shared__ int pfx[16][E_];
  __shared__ int soffs[E_ + 1];
  __shared__ int secnt[E_];
  const int tid = threadIdx.x;
  const int wave = tid >> 6, lane = tid & 63;
  const unsigned long long lt = (1ull << lane) - 1ull;

  zbuf[tid] = 0u;   // 4KB of zeros for gemm1 pad rows

  int   mye[8];
  int   mylp[8];
  float myp[8];
  int run[E_];
#pragma unroll
  for (int e = 0; e < E_; ++e) run[e] = 0;

#pragma unroll
  for (int it = 0; it < 8; ++it) {
    int i = wave * 512 + it * 64 + lane;
    int e = sel[i];
    mye[it] = e;
    myp[it] = prob[i];
    int lp = 0;
#pragma unroll
    for (int ee = 0; ee < E_; ++ee) {
      unsigned long long m = __ballot(e == ee);
      if (e == ee) lp = run[ee] + __popcll(m & lt);
      run[ee] += __popcll(m);
    }
    mylp[it] = lp;
  }
#pragma unroll
  for (int ee = 0; ee < E_; ++ee)
    if (lane == ee) wcnt[wave][ee] = run[ee];
  __syncthreads();

  if (tid == 0) {
    int ro = 0;
#pragma unroll
    for (int e = 0; e < E_; ++e) {
      int c = 0;
      int r = ro;
      for (int w = 0; w < 16; ++w) { pfx[w][e] = r; r += wcnt[w][e]; c += wcnt[w][e]; }
      soffs[e] = ro; offs[e] = ro; secnt[e] = c;
      ro += (c + PAD - 1) & ~(PAD - 1);
    }
    soffs[E_] = ro; offs[E_] = ro;
  }
  __syncthreads();

#pragma unroll
  for (int it = 0; it < 8; ++it) {
    int i = wave * 512 + it * 64 + lane;
    int pos = pfx[wave][mye[it]] + mylp[it];
    ptok[pos]  = i >> 1;
    pprob[pos] = myp[it];
    tpos[i]    = pos;
  }
#pragma unroll
  for (int e = 0; e < E_; ++e) {
    int s = soffs[e] + secnt[e];
    int npad = soffs[e + 1] - s;
    if (tid < npad) { ptok[s + tid] = -1; pprob[s + tid] = 0.f; }
  }
}

// ---------------- GEMM1: H = silu(X Wg^T) * (X Wu^T) ----------------
// 64x64 tile, BK=64, single-buffered 24KB LDS, 1088 blocks (4.25/CU). R6 structure.
__global__ __launch_bounds__(256, 4) void gemm1_kernel(const unsigned short* __restrict__ Xb,
                                                       const unsigned short* __restrict__ Wg,
                                                       const unsigned short* __restrict__ Wu,
                                                       const int* __restrict__ ptok,
                                                       const int* __restrict__ offs,
                                                       const unsigned short* __restrict__ zbuf,
                                                       unsigned short* __restrict__ H) {
  __shared__ unsigned short As[PAD * BK];   // 8KB
  __shared__ unsigned short Bg[64 * BK];    // 8KB
  __shared__ unsigned short Bu[64 * BK];    // 8KB
  __shared__ int toks[PAD];

  const int wgid = (blockIdx.x & 7) * 136 + (blockIdx.x >> 3);
  const int bx = wgid >> 3;          // 0..135 : position tile
  const int by = wgid & 7;           // 0..7   : I-panel (64 cols)

  const int total = offs[E_];
  const int t0 = bx * PAD;
  if (t0 >= total) return;
  int e = 0;
#pragma unroll
  for (int i = 1; i < E_; ++i) if (offs[i] <= t0) e = i;

  const int tid  = threadIdx.x;
  const int lane = tid & 63;
  const int w    = tid >> 6;
  if (tid < PAD) toks[tid] = ptok[t0 + tid];
  __syncthreads();

  const int ib    = by * 64;
  const int gcol8 = (lane & 7) ^ (lane >> 3);  // pre-swizzled source column (16B units)

  const unsigned short* asrc[2];
  const unsigned short* bgsrc[2];
  const unsigned short* busrc[2];
#pragma unroll
  for (int i = 0; i < 2; ++i) {
    int r = w * 16 + i * 8 + (lane >> 3);
    int t = toks[r];
    asrc[i] = (t >= 0) ? (Xb + (size_t)t * D_ + gcol8 * 8) : (zbuf + gcol8 * 8);
    size_t rowoff = ((size_t)e * I_ + ib + r) * D_ + gcol8 * 8;
    bgsrc[i] = Wg + rowoff;
    busrc[i] = Wu + rowoff;
  }

  f32x4 accg[2][2], accu[2][2];
#pragma unroll
  for (int m = 0; m < 2; ++m)
#pragma unroll
    for (int n = 0; n < 2; ++n) {
      accg[m][n] = (f32x4){0.f, 0.f, 0.f, 0.f};
      accu[m][n] = (f32x4){0.f, 0.f, 0.f, 0.f};
    }

  const int wr = w >> 1, wc = w & 1;
  const int xr7 = lane & 7;

  for (int k0 = 0; k0 < D_; k0 += BK) {
#pragma unroll
    for (int i = 0; i < 2; ++i) {
      GLOAD_LDS16(asrc[i] + k0, &As[(w * 2 + i) * 512]);
      GLOAD_LDS16(bgsrc[i] + k0, &Bg[(w * 2 + i) * 512]);
      GLOAD_LDS16(busrc[i] + k0, &Bu[(w * 2 + i) * 512]);
    }
    __syncthreads();   // compiler drains vmcnt before barrier
#pragma unroll
    for (int kk = 0; kk < 2; ++kk) {
      const int uoff = ((kk * 4 + (lane >> 4)) ^ xr7) * 8;
      bf16x8 a[2], bg[2], bu[2];
#pragma unroll
      for (int m = 0; m < 2; ++m) {
        int row = wr * 32 + m * 16 + (lane & 15);
        a[m] = *reinterpret_cast<const bf16x8*>(&As[row * BK + uoff]);
      }
#pragma unroll
      for (int n = 0; n < 2; ++n) {
        int row = wc * 32 + n * 16 + (lane & 15);
        bg[n] = *reinterpret_cast<const bf16x8*>(&Bg[row * BK + uoff]);
        bu[n] = *reinterpret_cast<const bf16x8*>(&Bu[row * BK + uoff]);
      }
#pragma unroll
      for (int m = 0; m < 2; ++m)
#pragma unroll
        for (int n = 0; n < 2; ++n) {
          accg[m][n] = __builtin_amdgcn_mfma_f32_16x16x32_bf16(bg[n], a[m], accg[m][n], 0, 0, 0);
          accu[m][n] = __builtin_amdgcn_mfma_f32_16x16x32_bf16(bu[n], a[m], accu[m][n], 0, 0, 0);
        }
    }
    __syncthreads();
  }

  // swapped-operand C/D layout: position = lane&15, I-index = (lane>>4)*4 + reg
#pragma unroll
  for (int m = 0; m < 2; ++m) {
    const int trow = wr * 32 + m * 16 + (lane & 15);
#pragma unroll
    for (int n = 0; n < 2; ++n) {
      const int icb = ib + wc * 32 + n * 16 + (lane >> 4) * 4;
      ushort4 st;
      float g, uu, h;
      g = accg[m][n][0]; uu = accu[m][n][0]; h = (g / (1.f + __expf(-g))) * uu; st.x = f2bf(h);
      g = accg[m][n][1]; uu = accu[m][n][1]; h = (g / (1.f + __expf(-g))) * uu; st.y = f2bf(h);
      g = accg[m][n][2]; uu = accu[m][n][2]; h = (g / (1.f + __expf(-g))) * uu; st.z = f2bf(h);
      g = accg[m][n][3]; uu = accu[m][n][3]; h = (g / (1.f + __expf(-g))) * uu; st.w = f2bf(h);
      *reinterpret_cast<ushort4*>(&H[(size_t)(t0 + trow) * I_ + icb]) = st;
    }
  }
}

// ---------------- GEMM2: Opos[pos] = prob * (H Wd^T), Wd read as fp32 + inline cvt ----------------
// 64pos x 128D tile, BK=64. As dbuf (gload_lds), Bs single 16KB (reg-staged fp32 -> bf16).
__global__ __launch_bounds__(256, 4) void gemm2_kernel(const unsigned short* __restrict__ H,
                                                       const float* __restrict__ Wd,
                                                       const float* __restrict__ pprob,
                                                       const int* __restrict__ offs,
                                                       unsigned short* __restrict__ O) {
  __shared__ unsigned short As[2][PAD * BK];   // 2 x 8KB (H rows)
  __shared__ unsigned short Bs[128 * BK];      // 16KB (Wd rows, bf16 after cvt)
  __shared__ float probs[PAD];

  const int wgid = (blockIdx.x & 7) * 136 + (blockIdx.x >> 3);
  const int bx = wgid >> 3;          // 0..135 : position tile
  const int by = wgid & 7;           // 0..7   : D-panel (128 cols)

  const int total = offs[E_];
  const int t0 = bx * PAD;
  if (t0 >= total) return;
  int e = 0;
#pragma unroll
  for (int i = 1; i < E_; ++i) if (offs[i] <= t0) e = i;

  const int tid  = threadIdx.x;
  const int lane = tid & 63;
  const int w    = tid >> 6;
  if (tid < PAD) probs[tid] = pprob[t0 + tid];

  const int db    = by * 128;
  const int gcol8 = (lane & 7) ^ (lane >> 3);

  const unsigned short* asrc[2];
#pragma unroll
  for (int i = 0; i < 2; ++i) {
    int r = w * 16 + i * 8 + (lane >> 3);
    asrc[i] = H + (size_t)(t0 + r) * I_ + gcol8 * 8;
  }
  // B: thread covers Wd row brow = tid>>1 (0..127), fp32 cols (tid&1)*32 .. +32 within BK
  const int brow = tid >> 1;
  const float* bsrc = Wd + ((size_t)e * D_ + db + brow) * I_ + (tid & 1) * 32;
  int bw[4];
#pragma unroll
  for (int j = 0; j < 4; ++j)
    bw[j] = brow * 64 + ((((tid & 1) * 4 + j) ^ (brow & 7)) * 8);  // swizzled ushort offset

  f32x4 acc[2][4];
#pragma unroll
  for (int m = 0; m < 2; ++m)
#pragma unroll
    for (int n = 0; n < 4; ++n) acc[m][n] = (f32x4){0.f, 0.f, 0.f, 0.f};

  const int wr = w >> 1, wc = w & 1;
  const int xr7 = lane & 7;

  float4 bv[8];
#define B_LOAD(k0)                                                             \
  do {                                                                         \
    _Pragma("unroll") for (int q = 0; q < 8; ++q)                              \
        bv[q] = *reinterpret_cast<const float4*>(bsrc + (k0) + q * 4);         \
  } while (0)
#define B_CVT_WRITE                                                            \
  do {                                                                         \
    _Pragma("unroll") for (int j = 0; j < 4; ++j) {                            \
      uint4 wv;                                                                \
      wv.x = pk2(bv[2*j].x, bv[2*j].y);                                        \
      wv.y = pk2(bv[2*j].z, bv[2*j].w);                                        \
      wv.z = pk2(bv[2*j+1].x, bv[2*j+1].y);                                    \
      wv.w = pk2(bv[2*j+1].z, bv[2*j+1].w);                                    \
      *reinterpret_cast<uint4*>(&Bs[bw[j]]) = wv;                              \
    }                                                                          \
  } while (0)
#define COMPUTE2(p)                                                            \
  do {                                                                         \
    _Pragma("unroll") for (int kk = 0; kk < 2; ++kk) {                         \
      const int uoff = ((kk * 4 + (lane >> 4)) ^ xr7) * 8;                     \
      bf16x8 a[2], bb[4];                                                      \
      _Pragma("unroll") for (int m = 0; m < 2; ++m) {                          \
        int row = wr * 32 + m * 16 + (lane & 15);                              \
        a[m] = *reinterpret_cast<const bf16x8*>(&As[p][row * BK + uoff]);      \
      }                                                                        \
      _Pragma("unroll") for (int n = 0; n < 4; ++n) {                          \
        int row = wc * 64 + n * 16 + (lane & 15);                              \
        bb[n] = *reinterpret_cast<const bf16x8*>(&Bs[row * BK + uoff]);        \
      }                                                                        \
      _Pragma("unroll") for (int m = 0; m < 2; ++m)                            \
        _Pragma("unroll") for (int n = 0; n < 4; ++n)                          \
          acc[m][n] = __builtin_amdgcn_mfma_f32_16x16x32_bf16(bb[n], a[m], acc[m][n], 0, 0, 0); \
    }                                                                          \
  } while (0)

  // prologue: stage step 0
  B_LOAD(0);
#pragma unroll
  for (int i = 0; i < 2; ++i) GLOAD_LDS16(asrc[i] + 0, &As[0][(w * 2 + i) * 512]);
  B_CVT_WRITE;
  __syncthreads();   // drains vmcnt (A glds) + lgkm (ds_writes), buffer 0 ready

  const int NK = I_ / BK;   // 8
  for (int t = 0; t < NK; ++t) {
    const int p = t & 1;
    if (t + 1 < NK) {
      B_LOAD((t + 1) * BK);                       // fp32 regs, in flight across compute
#pragma unroll
      for (int i = 0; i < 2; ++i)
        GLOAD_LDS16(asrc[i] + (t + 1) * BK, &As[p ^ 1][(w * 2 + i) * 512]);
      __builtin_amdgcn_sched_barrier(0);          // keep loads above compute
    }
    COMPUTE2(p);
    if (t + 1 < NK) {
      __builtin_amdgcn_sched_barrier(0);          // keep cvt below compute
      __syncthreads();                            // all waves done reading Bs (step t)
      B_CVT_WRITE;                                // cvt waits B regs (data dep), writes Bs(t+1)
      __syncthreads();                            // Bs + As[p^1] ready (drains lgkm+vm)
    }
  }

#pragma unroll
  for (int m = 0; m < 2; ++m) {
    const int trow = wr * 32 + m * 16 + (lane & 15);
    const float p = probs[trow];
#pragma unroll
    for (int n = 0; n < 4; ++n) {
      const int dcb = db + wc * 64 + n * 16 + (lane >> 4) * 4;
      ushort4 v;
      v.x = f2bf(acc[m][n][0] * p); v.y = f2bf(acc[m][n][1] * p);
      v.z = f2bf(acc[m][n][2] * p); v.w = f2bf(acc[m][n][3] * p);
      *reinterpret_cast<ushort4*>(&O[(size_t)(t0 + trow) * D_ + dcb]) = v;
    }
  }
#undef B_LOAD
#undef B_CVT_WRITE
#undef COMPUTE2
}

// ---------------- combine: out[t] = O[pos0] + O[pos1] (bf16 in, fp32 out) ----------------
__global__ __launch_bounds__(256) void combine_kernel(const unsigned short* __restrict__ O,
                                                      const int* __restrict__ tpos,
                                                      float* __restrict__ out) {
  const int t = blockIdx.x;
  const int c = threadIdx.x;
  const int p0 = tpos[2 * t], p1 = tpos[2 * t + 1];
  const ushort4 a = reinterpret_cast<const ushort4*>(O + (size_t)p0 * D_)[c];
  const ushort4 b = reinterpret_cast<const ushort4*>(O + (size_t)p1 * D_)[c];
  float4 r;
  r.x = bf2f(a.x) + bf2f(b.x); r.y = bf2f(a.y) + bf2f(b.y);
  r.z = bf2f(a.z) + bf2f(b.z); r.w = bf2f(a.w) + bf2f(b.w);
  reinterpret_cast<float4*>(out + (size_t)t * D_)[c] = r;
}

extern "C" void kernel_launch(void* const* d_in, const int* in_sizes, int n_in,
                              void* d_out, int out_size, void* d_ws, size_t ws_size,
                              hipStream_t stream) {
  const float* x  = (const float*)d_in[0];
  const float* rw = (const float*)d_in[1];
  const float* wg = (const float*)d_in[2];
  const float* wu = (const float*)d_in[3];
  const float* wd = (const float*)d_in[4];
  float* out    = (float*)d_out;
  float* logits = out + (size_t)N_TOK * D_;   // second output region

  char* ws = (char*)d_ws;
  int*   offs  = (int*)(ws + 64);
  unsigned short* zbuf = (unsigned short*)(ws + 256);       // 4KB zeros (plan writes)
  int*   sel   = (int*)  (ws + 4352);
  float* prob  = (float*)(ws + 37120);
  int*   ptok  = (int*)  (ws + 69888);    // CAP ints  -> ends 104704
  float* pprob = (float*)(ws + 104704);   // CAP floats -> ends 139520
  int*   tpos  = (int*)  (ws + 139520);   // 8192 ints  -> ends 172288
  unsigned short* Xb  = (unsigned short*)(ws + 172288);
  unsigned short* Wgb = Xb  + (size_t)N_TOK * D_;
  unsigned short* Wub = Wgb + WSZ;
  unsigned short* Hb  = Wub + WSZ;                          // [CAP, I_] bf16
  unsigned short* Opos = Hb + (size_t)CAP * I_;             // [CAP, D_] bf16

  prep_kernel<<<2 * 4096 + N_TOK / 4, 256, 0, stream>>>(x, rw, wg, wu,
                                                        logits, sel, prob, Xb, Wgb);
  plan_kernel<<<1, 1024, 0, stream>>>(sel, prob, offs, ptok, pprob, tpos, (unsigned int*)zbuf);
  gemm1_kernel<<<NBX * 8, 256, 0, stream>>>(Xb, Wgb, Wub, ptok, offs, zbuf, Hb);
  gemm2_kernel<<<NBX * 8, 256, 0, stream>>>(Hb, wd, pprob, offs, Opos);
  combine_kernel<<<N_TOK, 256, 0, stream>>>(Opos, tpos, out);
}

// Round 9
// 91.753 us; speedup vs baseline: 1.3013x; 1.3013x over previous
//
#include <hip/hip_runtime.h>
#include <cstdint>

// Problem constants
#define N_TOK 4096   // B*T
#define D_    1024
#define E_    8
#define I_    512
#define KTOP  2
#define PAD   64     // expert segments padded to 64 (tile M)
#define BK    64     // K-step
#define CAP   (N_TOK*KTOP + E_*PAD)   // 8704 max padded positions
#define NBX   (CAP / PAD)             // 136 position tiles (17 per XCD)
#define WSZ   ((size_t)E_ * I_ * D_)  // one weight's element count

typedef __attribute__((ext_vector_type(16))) float f32x16;
typedef __attribute__((ext_vector_type(8)))  short bf16x8;

__device__ inline unsigned short f2bf(float f) {
  union { float f; uint32_t u; } v; v.f = f;
  uint32_t r = v.u + 0x7fffu + ((v.u >> 16) & 1u);
  return (unsigned short)(r >> 16);
}
__device__ inline float bf2f(unsigned short h) {
  union { uint32_t u; float f; } v; v.u = ((uint32_t)h) << 16;
  return v.f;
}

#define GLOAD_LDS16(gp, lp)                                                        \
  __builtin_amdgcn_global_load_lds((const __attribute__((address_space(1))) void*)(gp), \
                                   (__attribute__((address_space(3))) void*)(lp), 16, 0, 0)

// ---------------- prep: Wg/Wu/Wd converts (blocks 0..12287) ∥ router (12288..13311) ----------------
__global__ __launch_bounds__(256) void prep_kernel(const float* __restrict__ x,
                                                   const float* __restrict__ rw,
                                                   const float* __restrict__ wg,
                                                   const float* __restrict__ wu,
                                                   const float* __restrict__ wd,
                                                   float* __restrict__ logits,
                                                   int* __restrict__ sel,
                                                   float* __restrict__ prob,
                                                   unsigned short* __restrict__ Xb,
                                                   unsigned short* __restrict__ Wb) {
  int b = blockIdx.x;
  if (b < 3 * 4096) {
    const int y = b >> 12;
    const float* s = (y == 0) ? wg : (y == 1) ? wu : wd;
    unsigned short* d = Wb + (size_t)y * WSZ;
    const int i = (b & 4095) * 256 + threadIdx.x;
    const float4 v = reinterpret_cast<const float4*>(s)[i];
    ushort4 o;
    o.x = f2bf(v.x); o.y = f2bf(v.y); o.z = f2bf(v.z); o.w = f2bf(v.w);
    reinterpret_cast<ushort4*>(d)[i] = o;
    return;
  }
  b -= 3 * 4096;   // router: 1024 blocks, 4 tokens each
  const int lane = threadIdx.x & 63;
  const int tok  = b * 4 + (threadIdx.x >> 6);
  const float4* xr = reinterpret_cast<const float4*>(x + (size_t)tok * D_);
  float4 xv[4];
#pragma unroll
  for (int q = 0; q < 4; ++q) xv[q] = xr[q * 64 + lane];
  float acc[E_];
#pragma unroll
  for (int e = 0; e < E_; ++e) {
    const float4* wr = reinterpret_cast<const float4*>(rw + (size_t)e * D_);
    float s = 0.f;
#pragma unroll
    for (int q = 0; q < 4; ++q) {
      float4 wv = wr[q * 64 + lane];
      s += xv[q].x * wv.x + xv[q].y * wv.y + xv[q].z * wv.z + xv[q].w * wv.w;
    }
    acc[e] = s;
  }
  ushort4* xb = reinterpret_cast<ushort4*>(Xb + (size_t)tok * D_);
#pragma unroll
  for (int q = 0; q < 4; ++q) {
    ushort4 o;
    o.x = f2bf(xv[q].x); o.y = f2bf(xv[q].y); o.z = f2bf(xv[q].z); o.w = f2bf(xv[q].w);
    xb[q * 64 + lane] = o;
  }
#pragma unroll
  for (int e = 0; e < E_; ++e)
#pragma unroll
    for (int off = 32; off; off >>= 1) acc[e] += __shfl_xor(acc[e], off);
  if (lane == 0) {
    float v0 = -1e30f, v1 = -1e30f; int i0 = 0, i1 = 0;
#pragma unroll
    for (int e = 0; e < E_; ++e) {
      float v = acc[e];
      logits[(size_t)tok * E_ + e] = v;
      if (v > v0)      { v1 = v0; i1 = i0; v0 = v; i0 = e; }
      else if (v > v1) { v1 = v;  i1 = e; }
    }
    float t  = __expf(v1 - v0);
    sel[tok * 2] = i0; sel[tok * 2 + 1] = i1;
    prob[tok * 2] = 1.f / (1.f + t);
    prob[tok * 2 + 1] = t / (1.f + t);
  }
}

// ---------------- plan: counts (ballot), padded offsets, scatter, pads ----------------
__global__ __launch_bounds__(1024) void plan_kernel(const int* __restrict__ sel,
                                                    const float* __restrict__ prob,
                                                    int* __restrict__ offs,
                                                    int* __restrict__ ptok,
                                                    float* __restrict__ pprob,
                                                    int* __restrict__ tpos) {
  __shared__ int wcnt[16][E_];
  __shared__ int pfx[16][E_];
  __shared__ int soffs[E_ + 1];
  __shared__ int secnt[E_];
  const int tid = threadIdx.x;
  const int wave = tid >> 6, lane = tid & 63;
  const unsigned long long lt = (1ull << lane) - 1ull;

  int   mye[8];
  int   mylp[8];
  float myp[8];
  int run[E_];
#pragma unroll
  for (int e = 0; e < E_; ++e) run[e] = 0;

#pragma unroll
  for (int it = 0; it < 8; ++it) {
    int i = wave * 512 + it * 64 + lane;
    int e = sel[i];
    mye[it] = e;
    myp[it] = prob[i];
    int lp = 0;
#pragma unroll
    for (int ee = 0; ee < E_; ++ee) {
      unsigned long long m = __ballot(e == ee);
      if (e == ee) lp = run[ee] + __popcll(m & lt);
      run[ee] += __popcll(m);
    }
    mylp[it] = lp;
  }
#pragma unroll
  for (int ee = 0; ee < E_; ++ee)
    if (lane == ee) wcnt[wave][ee] = run[ee];
  __syncthreads();

  if (tid == 0) {
    int ro = 0;
#pragma unroll
    for (int e = 0; e < E_; ++e) {
      int c = 0;
      int r = ro;
      for (int w = 0; w < 16; ++w) { pfx[w][e] = r; r += wcnt[w][e]; c += wcnt[w][e]; }
      soffs[e] = ro; offs[e] = ro; secnt[e] = c;
      ro += (c + PAD - 1) & ~(PAD - 1);
    }
    soffs[E_] = ro; offs[E_] = ro;
  }
  __syncthreads();

#pragma unroll
  for (int it = 0; it < 8; ++it) {
    int i = wave * 512 + it * 64 + lane;
    int pos = pfx[wave][mye[it]] + mylp[it];
    ptok[pos]  = i >> 1;
    pprob[pos] = myp[it];
    tpos[i]    = pos;
  }
  // padding: token 0 (valid gather target), prob 0; pad Opos rows are never combined
#pragma unroll
  for (int e = 0; e < E_; ++e) {
    int s = soffs[e] + secnt[e];
    int npad = soffs[e + 1] - s;
    if (tid < npad) { ptok[s + tid] = 0; pprob[s + tid] = 0.f; }
  }
}

// ---------------- GEMM1: H = silu(X Wg^T) * (X Wu^T) ----------------
// 64x64 tile, BK=64, single-buffered 24KB LDS, 32x32x16 MFMA, 1088 blocks (4.25/CU).
__global__ __launch_bounds__(256, 4) void gemm1_kernel(const unsigned short* __restrict__ Xb,
                                                       const unsigned short* __restrict__ Wg,
                                                       const unsigned short* __restrict__ Wu,
                                                       const int* __restrict__ ptok,
                                                       const int* __restrict__ offs,
                                                       unsigned short* __restrict__ H) {
  __shared__ unsigned short As[PAD * BK];   // 8KB
  __shared__ unsigned short Bg[64 * BK];    // 8KB
  __shared__ unsigned short Bu[64 * BK];    // 8KB
  __shared__ int toks[PAD];

  const int wgid = (blockIdx.x & 7) * 136 + (blockIdx.x >> 3);
  const int bx = wgid >> 3;          // 0..135 : position tile
  const int by = wgid & 7;           // 0..7   : I-panel (64 cols)

  const int total = offs[E_];
  const int t0 = bx * PAD;
  if (t0 >= total) return;
  int e = 0;
#pragma unroll
  for (int i = 1; i < E_; ++i) if (offs[i] <= t0) e = i;

  const int tid  = threadIdx.x;
  const int lane = tid & 63;
  const int w    = tid >> 6;
  if (tid < PAD) toks[tid] = ptok[t0 + tid];
  __syncthreads();

  const int ib    = by * 64;
  const int gcol8 = (lane & 7) ^ (lane >> 3);  // pre-swizzled source column (16B units)

  const unsigned short* asrc[2];
  const unsigned short* bgsrc[2];
  const unsigned short* busrc[2];
#pragma unroll
  for (int i = 0; i < 2; ++i) {
    int r = w * 16 + i * 8 + (lane >> 3);
    asrc[i] = Xb + (size_t)toks[r] * D_ + gcol8 * 8;
    size_t rowoff = ((size_t)e * I_ + ib + r) * D_ + gcol8 * 8;
    bgsrc[i] = Wg + rowoff;
    busrc[i] = Wu + rowoff;
  }

  f32x16 accg = {0.f}, accu = {0.f};
#pragma unroll
  for (int j = 0; j < 16; ++j) { accg[j] = 0.f; accu[j] = 0.f; }

  const int wr = w >> 1, wc = w & 1;   // wave grid: 2 (pos halves) x 2 (I halves)
  const int xr7 = lane & 7;
  const int arow = wr * 32 + (lane & 31);   // LDS row for A fragment
  const int brow = wc * 32 + (lane & 31);   // LDS row for B fragments

  for (int k0 = 0; k0 < D_; k0 += BK) {
#pragma unroll
    for (int i = 0; i < 2; ++i) {
      GLOAD_LDS16(asrc[i] + k0, &As[(w * 2 + i) * 512]);
      GLOAD_LDS16(bgsrc[i] + k0, &Bg[(w * 2 + i) * 512]);
      GLOAD_LDS16(busrc[i] + k0, &Bu[(w * 2 + i) * 512]);
    }
    __syncthreads();   // compiler drains vmcnt before barrier
#pragma unroll
    for (int sk = 0; sk < 4; ++sk) {
      const int uoff = ((sk * 2 + (lane >> 5)) ^ xr7) * 8;
      bf16x8 a  = *reinterpret_cast<const bf16x8*>(&As[arow * BK + uoff]);
      bf16x8 bg = *reinterpret_cast<const bf16x8*>(&Bg[brow * BK + uoff]);
      bf16x8 bu = *reinterpret_cast<const bf16x8*>(&Bu[brow * BK + uoff]);
      accg = __builtin_amdgcn_mfma_f32_32x32x16_bf16(bg, a, accg, 0, 0, 0);
      accu = __builtin_amdgcn_mfma_f32_32x32x16_bf16(bu, a, accu, 0, 0, 0);
    }
    __syncthreads();
  }

  // swapped-operand 32x32 C/D: position = lane&31, I-idx = (reg&3)+8*(reg>>2)+4*(lane>>5)
  const int hrow = t0 + wr * 32 + (lane & 31);
#pragma unroll
  for (int q = 0; q < 4; ++q) {
    const int icb = ib + wc * 32 + q * 8 + (lane >> 5) * 4;
    ushort4 st;
    float g, uu, h;
    g = accg[q*4+0]; uu = accu[q*4+0]; h = (g / (1.f + __expf(-g))) * uu; st.x = f2bf(h);
    g = accg[q*4+1]; uu = accu[q*4+1]; h = (g / (1.f + __expf(-g))) * uu; st.y = f2bf(h);
    g = accg[q*4+2]; uu = accu[q*4+2]; h = (g / (1.f + __expf(-g))) * uu; st.z = f2bf(h);
    g = accg[q*4+3]; uu = accu[q*4+3]; h = (g / (1.f + __expf(-g))) * uu; st.w = f2bf(h);
    *reinterpret_cast<ushort4*>(&H[(size_t)hrow * I_ + icb]) = st;
  }
}

// ---------------- GEMM2: Opos[pos] = prob * (H Wd^T), bf16 out ----------------
// 64pos x 128D tile, BK=64, single-buffered 24KB LDS, 32x32x16 MFMA.
__global__ __launch_bounds__(256, 4) void gemm2_kernel(const unsigned short* __restrict__ H,
                                                       const unsigned short* __restrict__ Wd,
                                                       const float* __restrict__ pprob,
                                                       const int* __restrict__ offs,
                                                       unsigned short* __restrict__ O) {
  __shared__ unsigned short As[PAD * BK];   // 8KB (H rows)
  __shared__ unsigned short Bs[128 * BK];   // 16KB (Wd rows)
  __shared__ float probs[PAD];

  const int wgid = (blockIdx.x & 7) * 136 + (blockIdx.x >> 3);
  const int bx = wgid >> 3;          // 0..135 : position tile
  const int by = wgid & 7;           // 0..7   : D-panel (128 cols)

  const int total = offs[E_];
  const int t0 = bx * PAD;
  if (t0 >= total) return;
  int e = 0;
#pragma unroll
  for (int i = 1; i < E_; ++i) if (offs[i] <= t0) e = i;

  const int tid  = threadIdx.x;
  const int lane = tid & 63;
  const int w    = tid >> 6;
  if (tid < PAD) probs[tid] = pprob[t0 + tid];
  __syncthreads();

  const int db    = by * 128;
  const int gcol8 = (lane & 7) ^ (lane >> 3);

  const unsigned short* asrc[2];
#pragma unroll
  for (int i = 0; i < 2; ++i) {
    int r = w * 16 + i * 8 + (lane >> 3);
    asrc[i] = H + (size_t)(t0 + r) * I_ + gcol8 * 8;
  }
  const unsigned short* bsrc[4];
#pragma unroll
  for (int i = 0; i < 4; ++i) {
    int r = w * 32 + i * 8 + (lane >> 3);
    bsrc[i] = Wd + ((size_t)e * D_ + db + r) * I_ + gcol8 * 8;
  }

  f32x16 acc0 = {0.f}, acc1 = {0.f};
#pragma unroll
  for (int j = 0; j < 16; ++j) { acc0[j] = 0.f; acc1[j] = 0.f; }

  const int wr = w >> 1, wc = w & 1;   // wave grid: 2 (pos halves) x 2 (D halves, 64 each)
  const int xr7 = lane & 7;
  const int arow  = wr * 32 + (lane & 31);
  const int brow0 = wc * 64 + (lane & 31);
  const int brow1 = wc * 64 + 32 + (lane & 31);

  for (int k0 = 0; k0 < I_; k0 += BK) {
#pragma unroll
    for (int i = 0; i < 2; ++i) GLOAD_LDS16(asrc[i] + k0, &As[(w * 2 + i) * 512]);
#pragma unroll
    for (int i = 0; i < 4; ++i) GLOAD_LDS16(bsrc[i] + k0, &Bs[(w * 4 + i) * 512]);
    __syncthreads();
#pragma unroll
    for (int sk = 0; sk < 4; ++sk) {
      const int uoff = ((sk * 2 + (lane >> 5)) ^ xr7) * 8;
      bf16x8 a  = *reinterpret_cast<const bf16x8*>(&As[arow * BK + uoff]);
      bf16x8 b0 = *reinterpret_cast<const bf16x8*>(&Bs[brow0 * BK + uoff]);
      bf16x8 b1 = *reinterpret_cast<const bf16x8*>(&Bs[brow1 * BK + uoff]);
      acc0 = __builtin_amdgcn_mfma_f32_32x32x16_bf16(b0, a, acc0, 0, 0, 0);
      acc1 = __builtin_amdgcn_mfma_f32_32x32x16_bf16(b1, a, acc1, 0, 0, 0);
    }
    __syncthreads();
  }

  const int prow = wr * 32 + (lane & 31);
  const float p = probs[prow];
  const int orow = t0 + prow;
#pragma unroll
  for (int q = 0; q < 4; ++q) {
    const int dcb0 = db + wc * 64 + q * 8 + (lane >> 5) * 4;
    ushort4 v;
    v.x = f2bf(acc0[q*4+0] * p); v.y = f2bf(acc0[q*4+1] * p);
    v.z = f2bf(acc0[q*4+2] * p); v.w = f2bf(acc0[q*4+3] * p);
    *reinterpret_cast<ushort4*>(&O[(size_t)orow * D_ + dcb0]) = v;
    ushort4 v1;
    v1.x = f2bf(acc1[q*4+0] * p); v1.y = f2bf(acc1[q*4+1] * p);
    v1.z = f2bf(acc1[q*4+2] * p); v1.w = f2bf(acc1[q*4+3] * p);
    *reinterpret_cast<ushort4*>(&O[(size_t)orow * D_ + dcb0 + 32]) = v1;
  }
}

// ---------------- combine: out[t] = O[pos0] + O[pos1] (bf16 in, fp32 out) ----------------
__global__ __launch_bounds__(256) void combine_kernel(const unsigned short* __restrict__ O,
                                                      const int* __restrict__ tpos,
                                                      float* __restrict__ out) {
  const int t = blockIdx.x;
  const int c = threadIdx.x;
  const int p0 = tpos[2 * t], p1 = tpos[2 * t + 1];
  const ushort4 a = reinterpret_cast<const ushort4*>(O + (size_t)p0 * D_)[c];
  const ushort4 b = reinterpret_cast<const ushort4*>(O + (size_t)p1 * D_)[c];
  float4 r;
  r.x = bf2f(a.x) + bf2f(b.x); r.y = bf2f(a.y) + bf2f(b.y);
  r.z = bf2f(a.z) + bf2f(b.z); r.w = bf2f(a.w) + bf2f(b.w);
  reinterpret_cast<float4*>(out + (size_t)t * D_)[c] = r;
}

extern "C" void kernel_launch(void* const* d_in, const int* in_sizes, int n_in,
                              void* d_out, int out_size, void* d_ws, size_t ws_size,
                              hipStream_t stream) {
  const float* x  = (const float*)d_in[0];
  const float* rw = (const float*)d_in[1];
  const float* wg = (const float*)d_in[2];
  const float* wu = (const float*)d_in[3];
  const float* wd = (const float*)d_in[4];
  float* out    = (float*)d_out;
  float* logits = out + (size_t)N_TOK * D_;   // second output region

  char* ws = (char*)d_ws;
  int*   offs  = (int*)(ws + 64);
  int*   sel   = (int*)  (ws + 4352);
  float* prob  = (float*)(ws + 37120);
  int*   ptok  = (int*)  (ws + 69888);    // CAP ints  -> ends 104704
  float* pprob = (float*)(ws + 104704);   // CAP floats -> ends 139520
  int*   tpos  = (int*)  (ws + 139520);   // 8192 ints  -> ends 172288
  unsigned short* Xb  = (unsigned short*)(ws + 172288);
  unsigned short* Wgb = Xb  + (size_t)N_TOK * D_;
  unsigned short* Wub = Wgb + WSZ;
  unsigned short* Wdb = Wub + WSZ;
  unsigned short* Hb  = Wdb + WSZ;                          // [CAP, I_] bf16
  unsigned short* Opos = Hb + (size_t)CAP * I_;             // [CAP, D_] bf16

  prep_kernel<<<3 * 4096 + N_TOK / 4, 256, 0, stream>>>(x, rw, wg, wu, wd,
                                                        logits, sel, prob, Xb, Wgb);
  plan_kernel<<<1, 1024, 0, stream>>>(sel, prob, offs, ptok, pprob, tpos);
  gemm1_kernel<<<NBX * 8, 256, 0, stream>>>(Xb, Wgb, Wub, ptok, offs, Hb);
  gemm2_kernel<<<NBX * 8, 256, 0, stream>>>(Hb, Wdb, pprob, offs, Opos);
  combine_kernel<<<N_TOK, 256, 0, stream>>>(Opos, tpos, out);
}